// Round 1
// baseline (86.697 us; speedup 1.0000x reference)
//
#include <hip/hip_runtime.h>
#include <hip/hip_bf16.h>

#define B_ 16
#define T_ 4096
#define IN_ 2
#define H_ 256
#define N_ 256

#define TWO_PI_F 6.28318530717958647692f
#define INV_TWO_PI_D 0.15915494309189533576888376337251

// ---------------------------------------------------------------------------
// Kernel 1: Cw[n] = sum_h Wh[h] * (C_re[h,n] + i C_im[h,n])
// grid: N_ blocks, 256 threads (one h per thread), block reduce.
// ---------------------------------------------------------------------------
__global__ __launch_bounds__(256) void cw_kernel(const float* __restrict__ C_re,
                                                 const float* __restrict__ C_im,
                                                 const float* __restrict__ Wh,
                                                 float2* __restrict__ Cw) {
    int n = blockIdx.x;
    int h = threadIdx.x;
    float w = Wh[h];
    float vr = w * C_re[h * N_ + n];
    float vi = w * C_im[h * N_ + n];
    // wave reduce (64 lanes)
    for (int off = 32; off > 0; off >>= 1) {
        vr += __shfl_down(vr, off);
        vi += __shfl_down(vi, off);
    }
    __shared__ float2 sred[4];
    int wid = threadIdx.x >> 6;
    int lane = threadIdx.x & 63;
    if (lane == 0) sred[wid] = make_float2(vr, vi);
    __syncthreads();
    if (threadIdx.x == 0) {
        float2 t = sred[0];
        t.x += sred[1].x + sred[2].x + sred[3].x;
        t.y += sred[1].y + sred[2].y + sred[3].y;
        Cw[n] = t;
    }
}

// ---------------------------------------------------------------------------
// Kernel 2: per (b,n): w_i = sum_{s<=t*} lam_n^{t*-s} x[b,s,i]  (closed form
// lam^k = exp(-k nu) * cis(k theta)); then
//   state = gamma*( (B_re+iB_im)[n,0]*w0 + (B_re+iB_im)[n,1]*w1 )
//   g[b,n] = Re(state * Cw[n])
// grid: (N_, B_) blocks, 256 threads striding over s.
// ---------------------------------------------------------------------------
__global__ __launch_bounds__(256) void lru_state_kernel(
        const float* __restrict__ x, const int* __restrict__ lengths,
        const float* __restrict__ nu_log, const float* __restrict__ theta_log,
        const float* __restrict__ B_re, const float* __restrict__ B_im,
        const float2* __restrict__ Cw, float* __restrict__ g) {
    const int n = blockIdx.x;
    const int b = blockIdx.y;
    const int L = lengths[b];
    const int tstar = L - 1;

    const float nu = __expf(nu_log[n]);
    const float th = __expf(theta_log[n]);
    const double threv = (double)th * INV_TWO_PI_D;  // theta / (2*pi)

    const float2* xb = ((const float2*)x) + (size_t)b * T_;

    float a0r = 0.f, a0i = 0.f, a1r = 0.f, a1i = 0.f;
    for (int s = threadIdx.x; s < L; s += 256) {
        int k = tstar - s;
        // phase = k*theta mod 2pi, reduced in fp64 (k*theta up to ~2.6e4 rad)
        double f = (double)k * threv;
        float r = (float)(f - rint(f));       // revolutions in [-0.5, 0.5]
        float ang = r * TWO_PI_F;             // radians in [-pi, pi]
        float sn, cs;
        __sincosf(ang, &sn, &cs);
        float e = __expf(-(float)k * nu);     // |lam|^k  (underflows to 0, fine)
        float vr = e * cs;
        float vi = e * sn;
        float2 xv = xb[s];
        a0r = fmaf(vr, xv.x, a0r);
        a0i = fmaf(vi, xv.x, a0i);
        a1r = fmaf(vr, xv.y, a1r);
        a1i = fmaf(vi, xv.y, a1i);
    }

    // block-reduce 4 floats
    for (int off = 32; off > 0; off >>= 1) {
        a0r += __shfl_down(a0r, off);
        a0i += __shfl_down(a0i, off);
        a1r += __shfl_down(a1r, off);
        a1i += __shfl_down(a1i, off);
    }
    __shared__ float4 sred[4];
    int wid = threadIdx.x >> 6;
    int lane = threadIdx.x & 63;
    if (lane == 0) sred[wid] = make_float4(a0r, a0i, a1r, a1i);
    __syncthreads();
    if (threadIdx.x == 0) {
        float4 t = sred[0];
        t.x += sred[1].x + sred[2].x + sred[3].x;
        t.y += sred[1].y + sred[2].y + sred[3].y;
        t.z += sred[1].z + sred[2].z + sred[3].z;
        t.w += sred[1].w + sred[2].w + sred[3].w;
        float gamma = sqrtf(1.f - __expf(-2.f * nu));
        float br0 = B_re[2 * n] * gamma, bi0 = B_im[2 * n] * gamma;
        float br1 = B_re[2 * n + 1] * gamma, bi1 = B_im[2 * n + 1] * gamma;
        // state = w0*Bm0 + w1*Bm1 (complex)
        float str = t.x * br0 - t.y * bi0 + t.z * br1 - t.w * bi1;
        float sti = t.x * bi0 + t.y * br0 + t.z * bi1 + t.w * br1;
        float2 cw = Cw[n];
        g[b * N_ + n] = str * cw.x - sti * cw.y;  // Re(state * Cw[n])
    }
}

// ---------------------------------------------------------------------------
// Kernel 3: out[b] = sum_n g[b,n] + sum_h Wh[h]*(D[h,:].x[b,t*,:]) + bh
// grid: B_ blocks, 256 threads (thread index doubles as n and h; N_==H_==256)
// ---------------------------------------------------------------------------
__global__ __launch_bounds__(256) void out_kernel(
        const float* __restrict__ g, const float* __restrict__ x,
        const int* __restrict__ lengths, const float* __restrict__ D,
        const float* __restrict__ Wh, const float* __restrict__ bh,
        float* __restrict__ out) {
    int b = blockIdx.x;
    int tstar = lengths[b] - 1;
    int h = threadIdx.x;
    float2 xv = ((const float2*)x)[(size_t)b * T_ + tstar];
    float v = g[b * N_ + h] + Wh[h] * (D[2 * h] * xv.x + D[2 * h + 1] * xv.y);
    for (int off = 32; off > 0; off >>= 1) v += __shfl_down(v, off);
    __shared__ float sred[4];
    int wid = threadIdx.x >> 6;
    int lane = threadIdx.x & 63;
    if (lane == 0) sred[wid] = v;
    __syncthreads();
    if (threadIdx.x == 0) {
        out[b] = sred[0] + sred[1] + sred[2] + sred[3] + bh[0];
    }
}

extern "C" void kernel_launch(void* const* d_in, const int* in_sizes, int n_in,
                              void* d_out, int out_size, void* d_ws, size_t ws_size,
                              hipStream_t stream) {
    const float* x         = (const float*)d_in[0];
    const int*   lengths   = (const int*)d_in[1];
    const float* nu_log    = (const float*)d_in[2];
    const float* theta_log = (const float*)d_in[3];
    const float* B_re      = (const float*)d_in[4];
    const float* B_im      = (const float*)d_in[5];
    const float* C_re      = (const float*)d_in[6];
    const float* C_im      = (const float*)d_in[7];
    const float* D         = (const float*)d_in[8];
    const float* Wh        = (const float*)d_in[9];
    const float* bh        = (const float*)d_in[10];
    float* out = (float*)d_out;

    // workspace layout: [Cw: N_ float2][g: B_*N_ float]
    float2* Cw = (float2*)d_ws;
    float*  g  = (float*)d_ws + 2 * N_;

    cw_kernel<<<N_, 256, 0, stream>>>(C_re, C_im, Wh, Cw);
    lru_state_kernel<<<dim3(N_, B_), 256, 0, stream>>>(x, lengths, nu_log, theta_log,
                                                       B_re, B_im, Cw, g);
    out_kernel<<<B_, 256, 0, stream>>>(g, x, lengths, D, Wh, bh, out);
}